// Round 13
// baseline (71.689 us; speedup 1.0000x reference)
//
#include <hip/hip_runtime.h>

#define T_OUT    524287
#define SIG_LEN  8388608
#define SPITCH   525376            // f16 per plane: m in [-544, 524832)
#define MOFF     544
#define NPLANES  32                // 16 phases x (re, im)
#define NST      66                // K=16 steps: d = 16u-16+p-kappa covers [0,1024)
#define RF16     1280              // ring f16 per plane (slot-reuse window verified)
#define RUNITS   160               // 16B units per plane
#define PLB      2560              // plane pitch bytes (ring & epilogue views)
#define NSIGBLK  2053              // prep: signal blocks, then afrag blocks

typedef _Float16 f16;
typedef _Float16 f16x8 __attribute__((ext_vector_type(8)));
typedef float    f32x16 __attribute__((ext_vector_type(16)));

// twiddles cos/sin(2*pi*k/16) — constexpr so compile-time indices fold to literals
#define TC1 0.9238795325112867f
#define TC2 0.7071067811865476f
#define TC3 0.3826834323650898f
constexpr float COS16[16] = { 1.f,  TC1,  TC2,  TC3, 0.f, -TC3, -TC2, -TC1,
                             -1.f, -TC1, -TC2, -TC3, 0.f,  TC3,  TC2,  TC1};
constexpr float SIN16[16] = { 0.f,  TC3,  TC2,  TC1, 1.f,  TC1,  TC2,  TC3,
                              0.f, -TC3, -TC2, -TC1,-1.f, -TC1, -TC2, -TC3};

__device__ __forceinline__ int phi(int vu) { return vu ^ ((vu >> 2) & 7); }  // ring unit swizzle
__device__ __forceinline__ int psi(int uu) { return uu ^ ((uu >> 3) & 7); }  // epilogue unit swizzle

// ============ merged prep: blocks [0,2053) = phase-split; [2053,2317) = A-frags ============
__global__ __launch_bounds__(256)
void prep_all(const float* __restrict__ sre, const float* __restrict__ sim,
              const float* __restrict__ coeff,
              f16* __restrict__ S16, f16* __restrict__ AF)
{
    __shared__ f16 lf[2 * 4104];
    const int tid = threadIdx.x;
    const int bid = blockIdx.x;

    if (bid >= NSIGBLK) {
        // ---- A-fragments for 32x32x16 (R10-verified) ----
        const int gid = (bid - NSIGBLK) * 256 + tid;
        if (gid >= 16 * NST * 64) return;
        const int lane = gid & 63;
        const int fi = gid >> 6;
        const int i = fi / NST, u = fi % NST;
        const int p = lane & 31, g = lane >> 5;
        f16 v[8];
        #pragma unroll
        for (int e = 0; e < 8; ++e) {
            const int d = 16 * u - 16 + p - (8 * g + e);
            v[e] = (d >= 0 && d < 1024) ? (f16)coeff[16 * d + i] : (f16)0.f;
        }
        *reinterpret_cast<f16x8*>(AF + (long)gid * 8) = *reinterpret_cast<const f16x8*>(v);
        return;
    }

    // ---- phase-split signal to f16 planes (R9-verified) ----
    const int M0 = -544 + 256 * bid;
    const long N0 = 16L * M0 - 16;

    #pragma unroll
    for (int c = 0; c < 8; ++c) {
        const int e = c >> 2, cc = c & 3;
        const int k = 4 * (tid + 256 * cc);
        const long n = N0 + k;
        const float* src = e ? sim : sre;
        float4 v = make_float4(0.f, 0.f, 0.f, 0.f);
        if (n >= 0 && n + 4 <= SIG_LEN) {
            v = *reinterpret_cast<const float4*>(src + n);
        } else {
            if (n     >= 0 && n     < SIG_LEN) v.x = src[n];
            if (n + 1 >= 0 && n + 1 < SIG_LEN) v.y = src[n + 1];
            if (n + 2 >= 0 && n + 2 < SIG_LEN) v.z = src[n + 2];
            if (n + 3 >= 0 && n + 3 < SIG_LEN) v.w = src[n + 3];
        }
        f16 h[4] = {(f16)v.x, (f16)v.y, (f16)v.z, (f16)v.w};
        *reinterpret_cast<uint2*>(&lf[e * 4104 + k]) = *reinterpret_cast<const uint2*>(h);
    }
    if (tid < 2) {
        const long n = N0 + 4096;
        const float x = (n >= 0 && n < SIG_LEN) ? (tid ? sim[n] : sre[n]) : 0.f;
        lf[tid * 4104 + 4096] = (f16)x;
    }
    __syncthreads();

    const int pl = tid & 31, i = pl >> 1, e = pl & 1;
    #pragma unroll
    for (int q = 0; q < 4; ++q) {
        const int a = (tid >> 5) + 8 * q;
        const int mr = M0 + 8 * a;
        if (mr + 8 <= 524832) {
            f16 h[8];
            #pragma unroll
            for (int j = 0; j < 8; ++j)
                h[j] = lf[e * 4104 + 128 * a + 16 * j + 16 - i];
            *reinterpret_cast<uint4*>(S16 + (long)pl * SPITCH + (MOFF + mr)) =
                *reinterpret_cast<const uint4*>(h);
        }
    }
}

// ============ main: 32x32x16 MFMA, 8 waves, BARRIER-FREE main loop ============
// Wave-locality proof: wave w's B-reads touch planes 4w..4w+3 only (rbase);
// wave w's threads (tid in [64w,64w+64)) stage spl = tid>>4 in [4w,4w+4) only;
// epilogue acc-writes land in rows 4w..4w+3 (own planes). No cross-wave LDS
// traffic until the epilogue transpose READ -> only the two epilogue barriers
// are semantically required. Per-wave write->read ordering is enforced by the
// compiler's conservative lgkmcnt on the aliasing LDS base.
__global__ __launch_bounds__(512, 4)
void wdm_mfma(const f16* __restrict__ S16, const f16* __restrict__ AF,
              float* __restrict__ out)
{
    extern __shared__ char lds_raw[];
    const int tid  = threadIdx.x;
    const int lane = tid & 63, w = tid >> 6;                        // 8 waves
    const int n = lane & 31, g = lane >> 5;
    const int tile = ((blockIdx.x & 7) << 6) + (blockIdx.x >> 3);   // XCD swizzle
    const int t0 = tile << 10;                                      // 1024 t per block

    // staging role: plane spl (32 planes x 16 threads), 1 unit/thread/k-block
    const int spl = tid >> 4, ss = tid & 15;
    const f16* gsrc = S16 + (long)spl * SPITCH + MOFF;
    char* ringpl = lds_raw + spl * PLB;
    const int sx = spl & 7;                                         // write-col XOR

    // prologue: stage m in [t0+416, t0+1567] (144 units/plane, 9/thread)
    #pragma unroll
    for (int jj = 0; jj < 9; ++jj) {
        const int m0 = t0 + 416 + 8 * (ss + 16 * jj);
        const uint4 v = *reinterpret_cast<const uint4*>(gsrc + m0);
        const int vu = (int)((unsigned)m0 % RF16) >> 3;
        *reinterpret_cast<uint4*>(ringpl + ((phi(vu) ^ sx) << 4)) = v;
    }
    // no barrier: prologue writes are wave-local, reads below are same-wave

    // A fragments: branches 2w, 2w+1; ping-pong, prefetch distance 2
    const f16x8* AFW = reinterpret_cast<const f16x8*>(AF) + ((long)(2 * w) * NST) * 64 + lane;
    f16x8 aA[2], aB[2];
    #pragma unroll
    for (int b = 0; b < 2; ++b) {
        aA[b] = AFW[(long)b * NST * 64];
        aB[b] = AFW[(long)b * NST * 64 + 64];
    }

    f32x16 acc[2][2];
    #pragma unroll
    for (int b = 0; b < 2; ++b)
        #pragma unroll
        for (int e = 0; e < 2; ++e)
            #pragma unroll
            for (int x = 0; x < 16; ++x) acc[b][e][x] = 0.f;

    // B read-unit tracker: m(u) = t0 + 528 - 16u + 32n + 8g
    int ru = (int)((unsigned)(t0 + 528 + 32 * n + 8 * g) % RF16) >> 3;
    const char* rbase = lds_raw + (w << 2) * PLB;   // plane 4w
    const int rx0 = (4 * w) & 7;                    // read-col XOR base

    auto STEP = [&](int u, f16x8 (&cur)[2], bool pf) {
        const int pr = phi(ru);
        f16x8 bv0 = *reinterpret_cast<const f16x8*>(rbase + 0 * PLB + ((pr ^ (rx0 + 0)) << 4));
        f16x8 bv1 = *reinterpret_cast<const f16x8*>(rbase + 1 * PLB + ((pr ^ (rx0 + 1)) << 4));
        f16x8 bv2 = *reinterpret_cast<const f16x8*>(rbase + 2 * PLB + ((pr ^ (rx0 + 2)) << 4));
        f16x8 bv3 = *reinterpret_cast<const f16x8*>(rbase + 3 * PLB + ((pr ^ (rx0 + 3)) << 4));
        __builtin_amdgcn_s_setprio(1);
        acc[0][0] = __builtin_amdgcn_mfma_f32_32x32x16_f16(cur[0], bv0, acc[0][0], 0, 0, 0);
        acc[0][1] = __builtin_amdgcn_mfma_f32_32x32x16_f16(cur[0], bv1, acc[0][1], 0, 0, 0);
        acc[1][0] = __builtin_amdgcn_mfma_f32_32x32x16_f16(cur[1], bv2, acc[1][0], 0, 0, 0);
        acc[1][1] = __builtin_amdgcn_mfma_f32_32x32x16_f16(cur[1], bv3, acc[1][1], 0, 0, 0);
        __builtin_amdgcn_s_setprio(0);
        if (pf) {
            #pragma unroll
            for (int b = 0; b < 2; ++b)
                cur[b] = AFW[(long)b * NST * 64 + (long)(u + 2) * 64];
        }
        ru -= 2; if (ru < 0) ru += RUNITS;
    };

    // 8 stage blocks x 8 steps; T14 split; NO barriers (wave-local ring)
    #pragma unroll 1
    for (int k = 0; k < 8; ++k) {
        const int mb = t0 + 288 - 128 * k + 8 * ss;
        const int mc = (mb < -544) ? -544 : mb;      // OOB slots never read
        const uint4 sv = *reinterpret_cast<const uint4*>(gsrc + mc);
        STEP(8 * k + 0, aA, true);  STEP(8 * k + 1, aB, true);
        STEP(8 * k + 2, aA, true);  STEP(8 * k + 3, aB, true);
        STEP(8 * k + 4, aA, true);  STEP(8 * k + 5, aB, true);
        STEP(8 * k + 6, aA, true);  STEP(8 * k + 7, aB, true);
        const int vu = (int)((unsigned)(mb + 5120) % RF16) >> 3;
        *reinterpret_cast<uint4*>(ringpl + ((phi(vu) ^ sx) << 4)) = sv;
    }
    STEP(64, aA, false);
    STEP(65, aB, false);

    // ---- epilogue: two 512-t halves through psi-swizzled LDS transpose ----
    // (acc-writes land in the wave's own planes; barrier needed only before
    //  the cross-wave transpose read and between halves)
    float* uf = reinterpret_cast<float*>(lds_raw);     // [32][640] f32 view
    const int np = n & 15;
    #pragma unroll 1
    for (int h = 0; h < 2; ++h) {
        if ((n >> 4) == h) {
            #pragma unroll
            for (int b = 0; b < 2; ++b)
                #pragma unroll
                for (int e = 0; e < 2; ++e) {
                    float* up = uf + ((w << 2) + 2 * b + e) * 640;
                    #pragma unroll
                    for (int j = 0; j < 4; ++j) {
                        const int uu = 8 * np + g + 2 * j;   // t_local = 4*uu + c
                        float4 val;
                        val.x = acc[b][e][4 * j + 0]; val.y = acc[b][e][4 * j + 1];
                        val.z = acc[b][e][4 * j + 2]; val.w = acc[b][e][4 * j + 3];
                        *reinterpret_cast<float4*>(up + psi(uu) * 4) = val;
                    }
                }
        }
        __syncthreads();
        {
            const int tl = tid;                         // 512 t per half, 1/thread
            const int foff = psi(tl >> 2) * 4 + (tl & 3);
            float ur[16], ui[16];
            #pragma unroll
            for (int i = 0; i < 16; ++i) {
                ur[i] = uf[(2 * i + 0) * 640 + foff];
                ui[i] = uf[(2 * i + 1) * 640 + foff];
            }
            // symmetry-folded real-output 16-pt inverse DFT
            float P[7], M[7];
            #pragma unroll
            for (int i = 1; i <= 7; ++i) {
                P[i - 1] = ur[i] + ur[16 - i];
                M[i - 1] = ui[i] - ui[16 - i];
            }
            float o[16];
            #pragma unroll
            for (int c = 0; c <= 8; ++c) {
                float e = (c & 1) ? (ur[0] - ur[8]) : (ur[0] + ur[8]);
                #pragma unroll
                for (int i = 1; i <= 7; ++i)
                    e = fmaf(COS16[(i * c) & 15], P[i - 1], e);
                o[c] = e;
            }
            #pragma unroll
            for (int c = 1; c <= 7; ++c) {
                float s = 0.f;
                #pragma unroll
                for (int i = 1; i <= 7; ++i)
                    s = fmaf(SIN16[(i * c) & 15], M[i - 1], s);
                o[16 - c] = o[c] + s;
                o[c]      = o[c] - s;
            }
            const int t = t0 + 512 * h + tl;
            if (t < T_OUT) {
                #pragma unroll
                for (int c = 0; c < 16; ++c)
                    out[(long)c * T_OUT + t] = o[c];
            }
        }
        if (h == 0) __syncthreads();
    }
}

extern "C" void kernel_launch(void* const* d_in, const int* in_sizes, int n_in,
                              void* d_out, int out_size, void* d_ws, size_t ws_size,
                              hipStream_t stream)
{
    const float* sre   = (const float*)d_in[0];
    const float* sim   = (const float*)d_in[1];
    const float* coeff = (const float*)d_in[2];
    float* out = (float*)d_out;

    f16* S16 = (f16*)d_ws;                         // 32 * 525376 * 2B = 33.62 MB
    f16* AF  = S16 + (long)NPLANES * SPITCH;       // 16*66*64*8 f16 = 1.03 MB

    // merged prep: 2053 signal blocks + 264 afrag blocks (16*66*64/256)
    prep_all<<<dim3(NSIGBLK + 264), dim3(256), 0, stream>>>(sre, sim, coeff, S16, AF);
    // 512 tiles x 1024 t; 512 threads (8 waves); LDS = 81920 B -> 2 blocks/CU
    wdm_mfma<<<dim3(512), dim3(512), NPLANES * PLB, stream>>>(S16, AF, out);
}